// Round 13
// baseline (379.177 us; speedup 1.0000x reference)
//
#include <hip/hip_runtime.h>
#include <hip/hip_bf16.h>

#define JN   17
#define DIM  512
#define HID  1024
#define MTOT 7776      // B*T = 32*243
#define MPAD 7936      // 31 * 256
#define NTHR 512

typedef __attribute__((ext_vector_type(8))) short s16x8;
typedef __attribute__((ext_vector_type(4))) float f32x4;
typedef unsigned short ushort_t;

__device__ __forceinline__ unsigned int f2bf(float f) {
    return (unsigned int)__builtin_bit_cast(unsigned short, __float2bfloat16(f));
}

// exact-erf GELU via Abramowitz-Stegun 7.1.26 (|err| < 1.5e-7)
__device__ __forceinline__ float gelu_erf(float h) {
    float ah = fabsf(h);
    float z  = ah * 0.7071067811865476f;
    float t  = __builtin_amdgcn_rcpf(fmaf(0.3275911f, z, 1.0f));
    float p  = fmaf(fmaf(fmaf(fmaf(1.061405429f, t, -1.453152027f), t,
                              1.421413741f), t, -0.284496736f), t, 0.254829592f);
    float er = 1.0f - p * t * __expf(-z * z);
    return fmaf(0.5f * ah, er, 0.5f * h);
}

// ============================================================================
// Prepass B: w1 [J][512][1024] fp32 -> w1s [J][kc=16][n=1024][p=4][8] bf16
// p = u ^ ((n>>1)&3)
// ============================================================================
__global__ __launch_bounds__(256)
void prep_w1(const float* __restrict__ w1, ushort_t* __restrict__ w1s) {
    int b  = blockIdx.x;
    int nq = b & 3;
    int kc = (b >> 2) & 15;
    int j  = b >> 6;
    int n  = nq * 256 + threadIdx.x;

    const float* src = w1 + ((size_t)j * DIM + kc * 32) * HID + n;
    ushort_t* dst = w1s + (((size_t)j * 16 + kc) * 1024 + n) * 32;

    #pragma unroll
    for (int u = 0; u < 4; ++u) {
        float v[8];
        #pragma unroll
        for (int e = 0; e < 8; ++e) v[e] = src[(u * 8 + e) * HID];
        uint4 qq;
        qq.x = f2bf(v[0]) | (f2bf(v[1]) << 16);
        qq.y = f2bf(v[2]) | (f2bf(v[3]) << 16);
        qq.z = f2bf(v[4]) | (f2bf(v[5]) << 16);
        qq.w = f2bf(v[6]) | (f2bf(v[7]) << 16);
        int p = u ^ ((n >> 1) & 3);
        *(uint4*)(dst + p * 8) = qq;
    }
}

// ============================================================================
// Prepass A: LayerNorm(x) -> xa [J][kc=16][m=MPAD][p=4][8] bf16, SWIZZLED
// p = u ^ (m&3) ^ ((m>>2)&3)  (v8-proven pair with the gemm's ds_read algebra)
// ============================================================================
__global__ __launch_bounds__(NTHR)
void prep_xn(const float* __restrict__ x,
             const float* __restrict__ gamma,
             const float* __restrict__ beta,
             ushort_t* __restrict__ xa)
{
    const int lane = threadIdx.x & 63;
    const int wv   = threadIdx.x >> 6;
    const int m    = blockIdx.x * 8 + wv;   // 972*8 = 7776 exactly
    const int j    = blockIdx.y;

    const float4* gp = (const float4*)(gamma + lane * 8);
    const float4* bp = (const float4*)(beta + lane * 8);
    float4 g0 = gp[0], g1 = gp[1];
    float4 e0 = bp[0], e1 = bp[1];

    const float4* xp = (const float4*)(x + ((size_t)m * JN + j) * DIM + lane * 8);
    float4 va = xp[0], vb = xp[1];

    float s  = ((va.x + va.y) + (va.z + va.w)) + ((vb.x + vb.y) + (vb.z + vb.w));
    float s2 = fmaf(va.x, va.x, fmaf(va.y, va.y, fmaf(va.z, va.z, fmaf(va.w, va.w,
               fmaf(vb.x, vb.x, fmaf(vb.y, vb.y, fmaf(vb.z, vb.z, vb.w * vb.w)))))));
    #pragma unroll
    for (int d = 1; d < 64; d <<= 1) {
        s  += __shfl_xor(s,  d);
        s2 += __shfl_xor(s2, d);
    }
    float mu  = s * (1.0f / 512.0f);
    float var = s2 * (1.0f / 512.0f) - mu * mu;
    float rs  = rsqrtf(var + 1e-5f);

    float v0 = fmaf((va.x - mu) * rs, g0.x, e0.x);
    float v1 = fmaf((va.y - mu) * rs, g0.y, e0.y);
    float v2 = fmaf((va.z - mu) * rs, g0.z, e0.z);
    float v3 = fmaf((va.w - mu) * rs, g0.w, e0.w);
    float v4 = fmaf((vb.x - mu) * rs, g1.x, e1.x);
    float v5 = fmaf((vb.y - mu) * rs, g1.y, e1.y);
    float v6 = fmaf((vb.z - mu) * rs, g1.z, e1.z);
    float v7 = fmaf((vb.w - mu) * rs, g1.w, e1.w);
    uint4 qq;
    qq.x = f2bf(v0) | (f2bf(v1) << 16);
    qq.y = f2bf(v2) | (f2bf(v3) << 16);
    qq.z = f2bf(v4) | (f2bf(v5) << 16);
    qq.w = f2bf(v6) | (f2bf(v7) << 16);

    int kc = lane >> 2;                                   // 0..15
    int p  = (lane & 3) ^ (m & 3) ^ ((m >> 2) & 3);
    *(uint4*)(xa + (((size_t)j * 16 + kc) * MPAD + m) * 32 + p * 8) = qq;
}

// ============================================================================
// v12 main GEMM: m201-cadence port. 256x256 tile, BK=64, 8 waves (2Mx4N, wave
// tile 128x64), 2x64KB LDS double buffer. Per K-tile: 4 phases, each
// {ds_read subtile; s_barrier; 16 MFMA (setprio); s_barrier}; all 8 stage
// DMAs front-loaded in phase 0; one vmcnt(0)+barrier per K-tile.
// LDS buffer layout (64KB): A kc0 16KB | A kc1 16KB | B kc0 16KB | B kc1 16KB,
// each slab [256 rows][4 units][8 bf16] copied verbatim from pre-swizzled ws.
// ============================================================================
#define SMEM_V12 131072
#define NWG12 (31 * 4 * JN)   // 2108 = 8*263 + 4

__global__ __launch_bounds__(NTHR, 2)
void pjh_gemm_v12(const ushort_t* __restrict__ xa,
                  const ushort_t* __restrict__ w1s,
                  const float* __restrict__ b1,
                  const float* __restrict__ w2,
                  float* __restrict__ ypart)
{
    extern __shared__ char smem[];
    const int tid  = threadIdx.x;
    const int lane = tid & 63;
    const int wv   = tid >> 6;   // 0..7
    const int wm   = wv >> 2;    // 0..1 : rows 128*wm
    const int wn   = wv & 3;     // 0..3 : cols 64*wn

    // m204 bijective XCD-chunked mapping (2108 = 8*263+4): nt3 fastest
    const int q   = NWG12 / 8, r = NWG12 % 8;   // 263, 4
    const int xcd = blockIdx.x & 7;
    const int lid = blockIdx.x >> 3;
    const int work = ((xcd < r) ? xcd * (q + 1) : r * (q + 1) + (xcd - r) * q) + lid;
    const int nt3  = work & 3;          // 256-wide N slice
    const int rest = work >> 2;
    const int mt   = rest % 31;         // 256-row M tile
    const int j    = rest / 31;

    // byte bases; per-kc-slab strides: xa MPAD*64, w1s 65536
    const char* xaJ = (const char*)xa  + (size_t)j * 16 * MPAD * 64 + (size_t)mt * 16384;
    const char* w1J = (const char*)w1s + (size_t)j * 16 * 65536   + (size_t)nt3 * 16384;
    const size_t xaK = (size_t)MPAD * 64;

    // ds_read byte offsets (within a buffer, kcs=0)
    int aoff[8];
    #pragma unroll
    for (int mf = 0; mf < 8; ++mf) {
        int ml = wm * 128 + mf * 16 + (lane & 15);
        int p  = (lane >> 4) ^ (ml & 3) ^ ((ml >> 2) & 3);
        aoff[mf] = ml * 64 + p * 16;
    }
    int boff[4];
    {
        int pB = (lane >> 4) ^ (((lane & 15) >> 1) & 3);
        #pragma unroll
        for (int nf = 0; nf < 4; ++nf) {
            int nl = wn * 64 + nf * 16 + (lane & 15);
            boff[nf] = 32768 + nl * 64 + pB * 16;
        }
    }

    const int cA = wv * 1024 + lane * 16;   // per-wave chunk offset within a slab

#define DMA(SRC, DST) __builtin_amdgcn_global_load_lds(                         \
        (const __attribute__((address_space(1))) unsigned int*)(SRC),           \
        (__attribute__((address_space(3))) unsigned int*)(DST), 16, 0, 0)

    // stage K-tile KT into buffer at byte base BN (8 DMAs per thread)
#define STAGE(KT, BN) do {                                                      \
        const char* sa0 = xaJ + (size_t)(2*(KT))   * xaK + cA;                  \
        const char* sa1 = xaJ + (size_t)(2*(KT)+1) * xaK + cA;                  \
        const char* sb0 = w1J + (size_t)(2*(KT))   * 65536 + cA;                \
        const char* sb1 = w1J + (size_t)(2*(KT)+1) * 65536 + cA;                \
        DMA(sa0,        smem + (BN) + cA);                                      \
        DMA(sa0 + 8192, smem + (BN) + 8192  + cA);                              \
        DMA(sa1,        smem + (BN) + 16384 + cA);                              \
        DMA(sa1 + 8192, smem + (BN) + 16384 + 8192 + cA);                       \
        DMA(sb0,        smem + (BN) + 32768 + cA);                              \
        DMA(sb0 + 8192, smem + (BN) + 32768 + 8192 + cA);                       \
        DMA(sb1,        smem + (BN) + 49152 + cA);                              \
        DMA(sb1 + 8192, smem + (BN) + 49152 + 8192 + cA);                       \
    } while (0)

    // one phase: mf pair (MB, MB+1), 16 MFMA
#define PHASE(MB, BC) do {                                                      \
        s16x8 aF0 = *(const s16x8*)(smem + (BC) + aoff[MB]);                    \
        s16x8 aF1 = *(const s16x8*)(smem + (BC) + aoff[MB] + 16384);            \
        s16x8 aF2 = *(const s16x8*)(smem + (BC) + aoff[MB + 1]);                \
        s16x8 aF3 = *(const s16x8*)(smem + (BC) + aoff[MB + 1] + 16384);        \
        __builtin_amdgcn_s_barrier();                                           \
        __builtin_amdgcn_s_setprio(1);                                          \
        _Pragma("unroll")                                                       \
        for (int nf = 0; nf < 4; ++nf) {                                        \
            acc[MB][nf]     = __builtin_amdgcn_mfma_f32_16x16x32_bf16(aF0, bF0[nf], acc[MB][nf], 0, 0, 0);     \
            acc[MB][nf]     = __builtin_amdgcn_mfma_f32_16x16x32_bf16(aF1, bF1[nf], acc[MB][nf], 0, 0, 0);     \
            acc[MB + 1][nf] = __builtin_amdgcn_mfma_f32_16x16x32_bf16(aF2, bF0[nf], acc[MB + 1][nf], 0, 0, 0); \
            acc[MB + 1][nf] = __builtin_amdgcn_mfma_f32_16x16x32_bf16(aF3, bF1[nf], acc[MB + 1][nf], 0, 0, 0); \
        }                                                                       \
        __builtin_amdgcn_s_setprio(0);                                          \
        __builtin_amdgcn_s_barrier();                                           \
    } while (0)

    const f32x4 zero4 = {0.f, 0.f, 0.f, 0.f};
    f32x4 acc[8][4];
    #pragma unroll
    for (int mf = 0; mf < 8; ++mf)
        #pragma unroll
        for (int nf = 0; nf < 4; ++nf) acc[mf][nf] = zero4;

    // prologue: buffer 0 <- K-tile 0
    STAGE(0, 0);
    asm volatile("s_waitcnt vmcnt(0)" ::: "memory");
    __builtin_amdgcn_s_barrier();

    #pragma unroll 1
    for (int kt = 0; kt < 8; ++kt) {
        const int bc = (kt & 1) * 65536;
        const int bn = bc ^ 65536;

        // phase 0 head: all B fragments + front-loaded staging of kt+1
        s16x8 bF0[4], bF1[4];
        #pragma unroll
        for (int nf = 0; nf < 4; ++nf) {
            bF0[nf] = *(const s16x8*)(smem + bc + boff[nf]);
            bF1[nf] = *(const s16x8*)(smem + bc + boff[nf] + 16384);
        }
        if (kt < 7) STAGE(kt + 1, bn);

        PHASE(0, bc);
        PHASE(2, bc);
        PHASE(4, bc);
        PHASE(6, bc);

        asm volatile("s_waitcnt vmcnt(0)" ::: "memory");   // kt+1 staged
        __builtin_amdgcn_s_barrier();
    }

    // ---- epilogue: bias + exact GELU + fc2 partials ----
    __syncthreads();   // LDS buffers dead; overlay Yp[4 wn][256 m][3]
    float* Yp = (float*)smem;

    float b1v[4], w20[4], w21[4], w22[4];
    #pragma unroll
    for (int nf = 0; nf < 4; ++nf) {
        int n = nt3 * 256 + wn * 64 + nf * 16 + (lane & 15);
        b1v[nf] = b1[j * HID + n];
        const float* w2p = w2 + ((size_t)j * HID + n) * 3;
        w20[nf] = w2p[0]; w21[nf] = w2p[1]; w22[nf] = w2p[2];
    }

    #pragma unroll
    for (int mf = 0; mf < 8; ++mf) {
        #pragma unroll
        for (int rr = 0; rr < 4; ++rr) {
            float s0 = 0.f, s1 = 0.f, s2 = 0.f;
            #pragma unroll
            for (int nf = 0; nf < 4; ++nf) {
                float gv = gelu_erf(acc[mf][nf][rr] + b1v[nf]);
                s0 = fmaf(gv, w20[nf], s0);
                s1 = fmaf(gv, w21[nf], s1);
                s2 = fmaf(gv, w22[nf], s2);
            }
            s0 += __shfl_xor(s0, 1); s0 += __shfl_xor(s0, 2);
            s0 += __shfl_xor(s0, 4); s0 += __shfl_xor(s0, 8);
            s1 += __shfl_xor(s1, 1); s1 += __shfl_xor(s1, 2);
            s1 += __shfl_xor(s1, 4); s1 += __shfl_xor(s1, 8);
            s2 += __shfl_xor(s2, 1); s2 += __shfl_xor(s2, 2);
            s2 += __shfl_xor(s2, 4); s2 += __shfl_xor(s2, 8);
            if ((lane & 15) == 0) {
                int m = wm * 128 + mf * 16 + (lane >> 4) * 4 + rr;
                Yp[(wn * 256 + m) * 3 + 0] = s0;
                Yp[(wn * 256 + m) * 3 + 1] = s1;
                Yp[(wn * 256 + m) * 3 + 2] = s2;
            }
        }
    }
    __syncthreads();

    for (int idx = tid; idx < 256 * 3; idx += NTHR) {
        int m = idx / 3;
        int o = idx - m * 3;
        int gr = mt * 256 + m;
        if (gr < MTOT) {
            float v = Yp[(m) * 3 + o] + Yp[(256 + m) * 3 + o]
                    + Yp[(512 + m) * 3 + o] + Yp[(768 + m) * 3 + o];
            ypart[(((size_t)nt3 * MPAD + gr) * JN + j) * 3 + o] = v;
        }
    }
#undef DMA
#undef STAGE
#undef PHASE
}

// ============================================================================
// fc2 reduce: out[gr][j][o] = b2[j][o] + sum_{s=0..3} ypart[s][gr][j][o]
// ============================================================================
__global__ __launch_bounds__(512)
void fc2_reduce(const float* __restrict__ ypart,
                const float* __restrict__ b2,
                float* __restrict__ out)
{
    int idx = blockIdx.x * 512 + threadIdx.x;      // = (gr*JN + j)*3 + o
    if (idx >= MTOT * JN * 3) return;
    int rest = idx / 3;
    int o = idx - rest * 3;
    int j = rest % JN;
    const size_t sl = (size_t)MPAD * JN * 3;
    float v = b2[j * 3 + o];
    #pragma unroll
    for (int s = 0; s < 4; ++s) v += ypart[s * sl + idx];
    out[idx] = v;
}

// ============================================================================
// Fallback v3: fused, A resident, B ring (needs only w1s ws)
// ============================================================================
#define BM3 96
#define A3_OFF 0
#define B3_OFF 98304
#define Y3_OFF 98304
#define SMEM_V3 163840

__global__ __launch_bounds__(NTHR, 2)
void pjh_fused_v3(const float* __restrict__ x,
                  const float* __restrict__ gamma,
                  const float* __restrict__ beta,
                  const ushort_t* __restrict__ w1s,
                  const float* __restrict__ b1,
                  const float* __restrict__ w2,
                  const float* __restrict__ b2,
                  float* __restrict__ out)
{
    extern __shared__ char smem[];
    const int tid  = threadIdx.x;
    const int lane = tid & 63;
    const int wv   = tid >> 6;
    const int wm   = wv >> 2;
    const int wn   = wv & 3;
    const int mt   = blockIdx.x;
    const int j    = blockIdx.y;

    const ushort_t* w1j = w1s + (size_t)j * 16 * 1024 * 32;

    #pragma unroll
    for (int tt = 0; tt < 2; ++tt) {
        const ushort_t* tb = w1j + (size_t)tt * 1024 * 32;
        #pragma unroll
        for (int qq = 0; qq < 2; ++qq) {
            const ushort_t* src = tb + (size_t)(wv * 2 + qq) * 512 + lane * 8;
            void* dst = smem + B3_OFF + tt * 16384 + (wv * 2 + qq) * 1024;
            __builtin_amdgcn_global_load_lds(
                (const __attribute__((address_space(1))) unsigned int*)src,
                (__attribute__((address_space(3))) unsigned int*)dst, 16, 0, 0);
        }
    }

    {
        const float4* gp  = (const float4*)(gamma + lane * 8);
        const float4* bpp = (const float4*)(beta + lane * 8);
        float4 g0 = gp[0], g1 = gp[1];
        float4 e0 = bpp[0], e1 = bpp[1];
        #pragma unroll
        for (int rb = 0; rb < 12; rb += 4) {
            float4 xs[4][2];
            #pragma unroll
            for (int rr = 0; rr < 4; ++rr) {
                int gr = mt * BM3 + wv * 12 + rb + rr;
                const float4* xp = (const float4*)(x + ((size_t)gr * JN + j) * DIM + lane * 8);
                xs[rr][0] = xp[0]; xs[rr][1] = xp[1];
            }
            #pragma unroll
            for (int rr = 0; rr < 4; ++rr) {
                int m = wv * 12 + rb + rr;
                float4 va = xs[rr][0], vb = xs[rr][1];
                float s  = ((va.x + va.y) + (va.z + va.w)) + ((vb.x + vb.y) + (vb.z + vb.w));
                float s2 = fmaf(va.x, va.x, fmaf(va.y, va.y, fmaf(va.z, va.z, fmaf(va.w, va.w,
                           fmaf(vb.x, vb.x, fmaf(vb.y, vb.y, fmaf(vb.z, vb.z, vb.w * vb.w)))))));
                #pragma unroll
                for (int d = 1; d < 64; d <<= 1) {
                    s  += __shfl_xor(s,  d);
                    s2 += __shfl_xor(s2, d);
                }
                float mu  = s * (1.0f / 512.0f);
                float var = s2 * (1.0f / 512.0f) - mu * mu;
                float rs  = rsqrtf(var + 1e-5f);
                float v0 = fmaf((va.x - mu) * rs, g0.x, e0.x);
                float v1 = fmaf((va.y - mu) * rs, g0.y, e0.y);
                float v2 = fmaf((va.z - mu) * rs, g0.z, e0.z);
                float v3 = fmaf((va.w - mu) * rs, g0.w, e0.w);
                float v4 = fmaf((vb.x - mu) * rs, g1.x, e1.x);
                float v5 = fmaf((vb.y - mu) * rs, g1.y, e1.y);
                float v6 = fmaf((vb.z - mu) * rs, g1.z, e1.z);
                float v7 = fmaf((vb.w - mu) * rs, g1.w, e1.w);
                uint4 qq;
                qq.x = f2bf(v0) | (f2bf(v1) << 16);
                qq.y = f2bf(v2) | (f2bf(v3) << 16);
                qq.z = f2bf(v4) | (f2bf(v5) << 16);
                qq.w = f2bf(v6) | (f2bf(v7) << 16);
                *(uint4*)(smem + A3_OFF + m * 1024 + ((lane ^ (m & 7)) * 16)) = qq;
            }
        }
    }

    __syncthreads();

    float yr[3][4][3];
    #pragma unroll
    for (int a = 0; a < 3; ++a)
        #pragma unroll
        for (int rr = 0; rr < 4; ++rr)
            #pragma unroll
            for (int o = 0; o < 3; ++o) yr[a][rr][o] = 0.f;

    const f32x4 zero4 = {0.f, 0.f, 0.f, 0.f};
    f32x4 acc[3][4];
    #pragma unroll
    for (int mf = 0; mf < 3; ++mf)
        #pragma unroll
        for (int nf = 0; nf < 4; ++nf) acc[mf][nf] = zero4;

    #pragma unroll 1
    for (int t = 0; t < 64; ++t) {
        if (t + 2 < 64) {
            int kc = (t + 2) & 15, nt = (t + 2) >> 4;
            const ushort_t* tb = w1j + ((size_t)kc * 1024 + nt * 256) * 32;
            int bb = ((t + 2) & 3) * 16384;
            #pragma unroll
            for (int qq = 0; qq < 2; ++qq) {
                const ushort_t* src = tb + (size_t)(wv * 2 + qq) * 512 + lane * 8;
                void* dst = smem + B3_OFF + bb + (wv * 2 + qq) * 1024;
                __builtin_amdgcn_global_load_lds(
                    (const __attribute__((address_space(1))) unsigned int*)src,
                    (__attribute__((address_space(3))) unsigned int*)dst, 16, 0, 0);
            }
        }

        int kc = t & 15;
        int bb = (t & 3) * 16384;
        int g  = lane >> 4;
        s16x8 aF[3], bF[4];
        #pragma unroll
        for (int mf = 0; mf < 3; ++mf) {
            int m  = wm * 48 + mf * 16 + (lane & 15);
            int ul = kc * 4 + g;
            aF[mf] = *(const s16x8*)(smem + A3_OFF + m * 1024 + ((ul ^ (m & 7)) * 16));
        }
        #pragma unroll
        for (int nf = 0; nf < 4; ++nf) {
            int nl = wn * 64 + nf * 16 + (lane & 15);
            int p  = g ^ ((nl >> 1) & 3);
            bF[nf] = *(const s16x8*)(smem + B3_OFF + bb + (nl * 4 + p) * 16);
        }

        __builtin_amdgcn_s_setprio(1);
        #pragma unroll
        for (int mf = 0; mf < 3; ++mf)
            #pragma unroll
            for (int nf = 0; nf < 4; ++nf)
                acc[mf][nf] = __builtin_amdgcn_mfma_f32_16x16x32_bf16(aF[mf], bF[nf], acc[mf][nf], 0, 0, 0);
        __builtin_amdgcn_s_setprio(0);

        if ((t & 15) == 15) {
            int nt = t >> 4;
            #pragma unroll
            for (int nf = 0; nf < 4; ++nf) {
                int n = nt * 256 + wn * 64 + nf * 16 + (lane & 15);
                float b1v = b1[j * HID + n];
                const float* w2p = w2 + ((size_t)j * HID + n) * 3;
                float w20 = w2p[0], w21 = w2p[1], w22 = w2p[2];
                #pragma unroll
                for (int mf = 0; mf < 3; ++mf) {
                    #pragma unroll
                    for (int rr = 0; rr < 4; ++rr) {
                        float gv = gelu_erf(acc[mf][nf][rr] + b1v);
                        yr[mf][rr][0] = fmaf(gv, w20, yr[mf][rr][0]);
                        yr[mf][rr][1] = fmaf(gv, w21, yr[mf][rr][1]);
                        yr[mf][rr][2] = fmaf(gv, w22, yr[mf][rr][2]);
                    }
                }
            }
            #pragma unroll
            for (int mf = 0; mf < 3; ++mf)
                #pragma unroll
                for (int nf = 0; nf < 4; ++nf)
                    acc[mf][nf] = zero4;
        }

        if (t < 62) {
            asm volatile("s_waitcnt vmcnt(2)" ::: "memory");
        } else {
            asm volatile("s_waitcnt vmcnt(0)" ::: "memory");
        }
        __builtin_amdgcn_s_barrier();
    }

    #pragma unroll
    for (int mf = 0; mf < 3; ++mf)
        #pragma unroll
        for (int rr = 0; rr < 4; ++rr)
            #pragma unroll
            for (int o = 0; o < 3; ++o) {
                float v = yr[mf][rr][o];
                v += __shfl_xor(v, 1);
                v += __shfl_xor(v, 2);
                v += __shfl_xor(v, 4);
                v += __shfl_xor(v, 8);
                yr[mf][rr][o] = v;
            }

    __syncthreads();

    float* Yp = (float*)(smem + Y3_OFF);
    if ((lane & 15) == 0) {
        int mrow = lane >> 4;
        #pragma unroll
        for (int mf = 0; mf < 3; ++mf)
            #pragma unroll
            for (int rr = 0; rr < 4; ++rr) {
                int m = wm * 48 + mf * 16 + mrow * 4 + rr;
                #pragma unroll
                for (int o = 0; o < 3; ++o)
                    Yp[(wn * BM3 + m) * 3 + o] = yr[mf][rr][o];
            }
    }
    __syncthreads();

    if (tid < BM3 * 3) {
        int m = tid / 3;
        int o = tid - m * 3;
        int gr = mt * BM3 + m;
        float v = Yp[m * 3 + o] + Yp[(BM3 + m) * 3 + o]
                + Yp[(2 * BM3 + m) * 3 + o] + Yp[(3 * BM3 + m) * 3 + o]
                + b2[j * 3 + o];
        out[((size_t)gr * JN + j) * 3 + o] = v;
    }
}

extern "C" void kernel_launch(void* const* d_in, const int* in_sizes, int n_in,
                              void* d_out, int out_size, void* d_ws, size_t ws_size,
                              hipStream_t stream) {
    (void)in_sizes; (void)n_in; (void)out_size;
    const float* x   = (const float*)d_in[0];
    const float* ga  = (const float*)d_in[1];
    const float* be  = (const float*)d_in[2];
    const float* w1  = (const float*)d_in[3];
    const float* b1  = (const float*)d_in[4];
    const float* w2  = (const float*)d_in[5];
    const float* b2  = (const float*)d_in[6];
    float* out = (float*)d_out;

    const size_t xa_bytes  = (size_t)JN * 16 * MPAD * 32 * sizeof(ushort_t);   // 138,149,888
    const size_t w1s_bytes = (size_t)JN * 16 * 1024 * 32 * sizeof(ushort_t);   // 17,825,792
    const size_t yp_bytes  = (size_t)4 * MPAD * JN * 3 * sizeof(float);        // 6,475,776

    if (ws_size >= xa_bytes + w1s_bytes + yp_bytes) {
        ushort_t* xa  = (ushort_t*)d_ws;
        ushort_t* w1s = (ushort_t*)((char*)d_ws + xa_bytes);
        float* ypart  = (float*)((char*)d_ws + xa_bytes + w1s_bytes);
        prep_xn<<<dim3(MTOT / 8, JN), NTHR, 0, stream>>>(x, ga, be, xa);
        prep_w1<<<JN * 16 * 4, 256, 0, stream>>>(w1, w1s);
        hipFuncSetAttribute((const void*)pjh_gemm_v12,
                            hipFuncAttributeMaxDynamicSharedMemorySize, SMEM_V12);
        pjh_gemm_v12<<<NWG12, NTHR, SMEM_V12, stream>>>(xa, w1s, b1, w2, ypart);
        fc2_reduce<<<(MTOT * JN * 3 + 511) / 512, 512, 0, stream>>>(ypart, b2, out);
    } else {
        ushort_t* w1s = (ushort_t*)d_ws;
        prep_w1<<<JN * 16 * 4, 256, 0, stream>>>(w1, w1s);
        hipFuncSetAttribute((const void*)pjh_fused_v3,
                            hipFuncAttributeMaxDynamicSharedMemorySize, SMEM_V3);
        dim3 grid(MTOT / BM3, JN);
        pjh_fused_v3<<<grid, NTHR, SMEM_V3, stream>>>(x, ga, be, w1s, b1, w2, b2, out);
    }
}

// Round 14
// 310.285 us; speedup vs baseline: 1.2220x; 1.2220x over previous
//
#include <hip/hip_runtime.h>
#include <hip/hip_bf16.h>

#define JN   17
#define DIM  512
#define HID  1024
#define MTOT 7776      // B*T = 32*243
#define MPAD 7808      // 61*128
#define NTHR 512

typedef __attribute__((ext_vector_type(8))) short s16x8;
typedef __attribute__((ext_vector_type(4))) float f32x4;
typedef unsigned short ushort_t;

__device__ __forceinline__ unsigned int f2bf(float f) {
    return (unsigned int)__builtin_bit_cast(unsigned short, __float2bfloat16(f));
}

// exact-erf GELU via Abramowitz-Stegun 7.1.26 (|err| < 1.5e-7)
__device__ __forceinline__ float gelu_erf(float h) {
    float ah = fabsf(h);
    float z  = ah * 0.7071067811865476f;
    float t  = __builtin_amdgcn_rcpf(fmaf(0.3275911f, z, 1.0f));
    float p  = fmaf(fmaf(fmaf(fmaf(1.061405429f, t, -1.453152027f), t,
                              1.421413741f), t, -0.284496736f), t, 0.254829592f);
    float er = 1.0f - p * t * __expf(-z * z);
    return fmaf(0.5f * ah, er, 0.5f * h);
}

// ============================================================================
// Prepass B: w1 [J][512][1024] fp32 -> w1s [J][kc=16][n=1024][p=4][8] bf16
// p = u ^ ((n>>1)&3)
// ============================================================================
__global__ __launch_bounds__(256)
void prep_w1(const float* __restrict__ w1, ushort_t* __restrict__ w1s) {
    int b  = blockIdx.x;
    int nq = b & 3;
    int kc = (b >> 2) & 15;
    int j  = b >> 6;
    int n  = nq * 256 + threadIdx.x;

    const float* src = w1 + ((size_t)j * DIM + kc * 32) * HID + n;
    ushort_t* dst = w1s + (((size_t)j * 16 + kc) * 1024 + n) * 32;

    #pragma unroll
    for (int u = 0; u < 4; ++u) {
        float v[8];
        #pragma unroll
        for (int e = 0; e < 8; ++e) v[e] = src[(u * 8 + e) * HID];
        uint4 qq;
        qq.x = f2bf(v[0]) | (f2bf(v[1]) << 16);
        qq.y = f2bf(v[2]) | (f2bf(v[3]) << 16);
        qq.z = f2bf(v[4]) | (f2bf(v[5]) << 16);
        qq.w = f2bf(v[6]) | (f2bf(v[7]) << 16);
        int p = u ^ ((n >> 1) & 3);
        *(uint4*)(dst + p * 8) = qq;
    }
}

// ============================================================================
// Prepass A: LayerNorm(x) -> xa [J][kc=16][m=MPAD][p=4][8] bf16, SWIZZLED
// p = u ^ (m&3) ^ ((m>>2)&3)
// ============================================================================
__global__ __launch_bounds__(NTHR)
void prep_xn(const float* __restrict__ x,
             const float* __restrict__ gamma,
             const float* __restrict__ beta,
             ushort_t* __restrict__ xa)
{
    const int lane = threadIdx.x & 63;
    const int wv   = threadIdx.x >> 6;
    const int m    = blockIdx.x * 8 + wv;   // 972*8 = 7776 exactly
    const int j    = blockIdx.y;

    const float4* gp = (const float4*)(gamma + lane * 8);
    const float4* bp = (const float4*)(beta + lane * 8);
    float4 g0 = gp[0], g1 = gp[1];
    float4 e0 = bp[0], e1 = bp[1];

    const float4* xp = (const float4*)(x + ((size_t)m * JN + j) * DIM + lane * 8);
    float4 va = xp[0], vb = xp[1];

    float s  = ((va.x + va.y) + (va.z + va.w)) + ((vb.x + vb.y) + (vb.z + vb.w));
    float s2 = fmaf(va.x, va.x, fmaf(va.y, va.y, fmaf(va.z, va.z, fmaf(va.w, va.w,
               fmaf(vb.x, vb.x, fmaf(vb.y, vb.y, fmaf(vb.z, vb.z, vb.w * vb.w)))))));
    #pragma unroll
    for (int d = 1; d < 64; d <<= 1) {
        s  += __shfl_xor(s,  d);
        s2 += __shfl_xor(s2, d);
    }
    float mu  = s * (1.0f / 512.0f);
    float var = s2 * (1.0f / 512.0f) - mu * mu;
    float rs  = rsqrtf(var + 1e-5f);

    float v0 = fmaf((va.x - mu) * rs, g0.x, e0.x);
    float v1 = fmaf((va.y - mu) * rs, g0.y, e0.y);
    float v2 = fmaf((va.z - mu) * rs, g0.z, e0.z);
    float v3 = fmaf((va.w - mu) * rs, g0.w, e0.w);
    float v4 = fmaf((vb.x - mu) * rs, g1.x, e1.x);
    float v5 = fmaf((vb.y - mu) * rs, g1.y, e1.y);
    float v6 = fmaf((vb.z - mu) * rs, g1.z, e1.z);
    float v7 = fmaf((vb.w - mu) * rs, g1.w, e1.w);
    uint4 qq;
    qq.x = f2bf(v0) | (f2bf(v1) << 16);
    qq.y = f2bf(v2) | (f2bf(v3) << 16);
    qq.z = f2bf(v4) | (f2bf(v5) << 16);
    qq.w = f2bf(v6) | (f2bf(v7) << 16);

    int kc = lane >> 2;                                   // 0..15
    int p  = (lane & 3) ^ (m & 3) ^ ((m >> 2) & 3);
    *(uint4*)(xa + (((size_t)j * 16 + kc) * MPAD + m) * 32 + p * 8) = qq;
}

// ============================================================================
// v13 main GEMM: exact m97 shape. 256-thr block (4 waves 2x2), tile 128x128,
// wave tile 64x64, 32KB LDS (2 x [A 8KB | B 8KB]), depth-1 global_load_lds +
// __syncthreads cadence, ~4 independent blocks/CU (stall decorrelation).
// ============================================================================
#define SMEM_V13 32768
#define NWG13 (61 * 8 * JN)   // 8296, divisible by 8

__global__ __launch_bounds__(256, 3)
void pjh_gemm_v13(const ushort_t* __restrict__ xa,
                  const ushort_t* __restrict__ w1s,
                  const float* __restrict__ b1,
                  const float* __restrict__ w2,
                  float* __restrict__ ypart)
{
    extern __shared__ char smem[];
    const int tid  = threadIdx.x;
    const int lane = tid & 63;
    const int wv   = tid >> 6;   // 0..3
    const int wm   = wv >> 1;    // 0..1 : rows 64*wm
    const int wn   = wv & 1;     // 0..1 : cols 64*wn

    // chunked XCD mapping (NWG13 % 8 == 0): nt2 fastest -> A-panel L2 reuse
    const int xcd  = blockIdx.x & 7;
    const int lid  = blockIdx.x >> 3;
    const int work = xcd * (NWG13 / 8) + lid;
    const int nt2  = work & 7;          // 128-wide N slice
    const int rest = work >> 3;
    const int mt   = rest % 61;         // 128-row M tile
    const int j    = rest / 61;

    // byte bases; per-kc-slab strides: xa MPAD*64, w1s 65536
    const char* xaJ = (const char*)xa  + (size_t)j * 16 * MPAD * 64 + (size_t)mt * 8192;
    const char* w1J = (const char*)w1s + (size_t)j * 16 * 65536   + (size_t)nt2 * 8192;
    const size_t xaK = (size_t)MPAD * 64;

    // ds_read byte offsets within a buffer (A at 0, B at 8192)
    const int g = lane >> 4;
    int aoff[4], boff[4];
    #pragma unroll
    for (int mf = 0; mf < 4; ++mf) {
        int ml = wm * 64 + mf * 16 + (lane & 15);
        int p  = g ^ (ml & 3) ^ ((ml >> 2) & 3);
        aoff[mf] = ml * 64 + p * 16;
    }
    {
        int pB = g ^ (((lane & 15) >> 1) & 3);
        #pragma unroll
        for (int nf = 0; nf < 4; ++nf) {
            int nl = wn * 64 + nf * 16 + (lane & 15);
            int p  = g ^ ((nl >> 1) & 3);
            boff[nf] = 8192 + nl * 64 + p * 16;
        }
        (void)pB;
    }

    const int cT = tid * 16;   // per-thread 16B chunk within an 8KB half-slab... (4KB x 256thr)

#define DMA(SRC, DST) __builtin_amdgcn_global_load_lds(                         \
        (const __attribute__((address_space(1))) unsigned int*)(SRC),           \
        (__attribute__((address_space(3))) unsigned int*)(DST), 16, 0, 0)

    // stage kc-step KC (A 8KB + B 8KB) into buffer at byte base BN
#define STAGE(KC, BN) do {                                                      \
        const char* sa = xaJ + (size_t)(KC) * xaK + cT;                         \
        const char* sb = w1J + (size_t)(KC) * 65536 + cT;                       \
        DMA(sa,        smem + (BN) + cT);                                       \
        DMA(sa + 4096, smem + (BN) + 4096 + cT);                                \
        DMA(sb,        smem + (BN) + 8192 + cT);                                \
        DMA(sb + 4096, smem + (BN) + 8192 + 4096 + cT);                         \
    } while (0)

#define STEP(BN) do {                                                           \
        s16x8 aF[4], bF[4];                                                     \
        _Pragma("unroll")                                                       \
        for (int mf = 0; mf < 4; ++mf)                                          \
            aF[mf] = *(const s16x8*)(smem + (BN) + aoff[mf]);                   \
        _Pragma("unroll")                                                       \
        for (int nf = 0; nf < 4; ++nf)                                          \
            bF[nf] = *(const s16x8*)(smem + (BN) + boff[nf]);                   \
        __builtin_amdgcn_s_setprio(1);                                          \
        _Pragma("unroll")                                                       \
        for (int mf = 0; mf < 4; ++mf)                                          \
            _Pragma("unroll")                                                   \
            for (int nf = 0; nf < 4; ++nf)                                      \
                acc[mf][nf] = __builtin_amdgcn_mfma_f32_16x16x32_bf16(aF[mf], bF[nf], acc[mf][nf], 0, 0, 0); \
        __builtin_amdgcn_s_setprio(0);                                          \
    } while (0)

    const f32x4 zero4 = {0.f, 0.f, 0.f, 0.f};
    f32x4 acc[4][4];
    #pragma unroll
    for (int mf = 0; mf < 4; ++mf)
        #pragma unroll
        for (int nf = 0; nf < 4; ++nf) acc[mf][nf] = zero4;

    STAGE(0, 0);
    __syncthreads();            // tile 0 resident

    #pragma unroll 1
    for (int t = 0; t < 16; ++t) {
        int bc = (t & 1) * 16384;
        if (t + 1 < 16) STAGE(t + 1, bc ^ 16384);   // loads fly under compute
        STEP(bc);
        __syncthreads();        // drains next tile's DMAs + guards buffer reuse
    }

    // ---- epilogue: bias + exact GELU + fc2 partials (register-lean) ----
    float* Yp = (float*)smem;   // overlay: [2 wn][128 m][3] floats = 3 KB

    float b1v[4], w20[4], w21[4], w22[4];
    #pragma unroll
    for (int nf = 0; nf < 4; ++nf) {
        int n = nt2 * 128 + wn * 64 + nf * 16 + (lane & 15);
        b1v[nf] = b1[j * HID + n];
        const float* w2p = w2 + ((size_t)j * HID + n) * 3;
        w20[nf] = w2p[0]; w21[nf] = w2p[1]; w22[nf] = w2p[2];
    }

    #pragma unroll
    for (int mf = 0; mf < 4; ++mf) {
        #pragma unroll
        for (int rr = 0; rr < 4; ++rr) {
            float s0 = 0.f, s1 = 0.f, s2 = 0.f;
            #pragma unroll
            for (int nf = 0; nf < 4; ++nf) {
                float gv = gelu_erf(acc[mf][nf][rr] + b1v[nf]);
                s0 = fmaf(gv, w20[nf], s0);
                s1 = fmaf(gv, w21[nf], s1);
                s2 = fmaf(gv, w22[nf], s2);
            }
            s0 += __shfl_xor(s0, 1); s0 += __shfl_xor(s0, 2);
            s0 += __shfl_xor(s0, 4); s0 += __shfl_xor(s0, 8);
            s1 += __shfl_xor(s1, 1); s1 += __shfl_xor(s1, 2);
            s1 += __shfl_xor(s1, 4); s1 += __shfl_xor(s1, 8);
            s2 += __shfl_xor(s2, 1); s2 += __shfl_xor(s2, 2);
            s2 += __shfl_xor(s2, 4); s2 += __shfl_xor(s2, 8);
            if ((lane & 15) == 0) {
                int m = wm * 64 + mf * 16 + (lane >> 4) * 4 + rr;
                Yp[(wn * 128 + m) * 3 + 0] = s0;
                Yp[(wn * 128 + m) * 3 + 1] = s1;
                Yp[(wn * 128 + m) * 3 + 2] = s2;
            }
        }
    }
    __syncthreads();

    for (int idx = tid; idx < 128 * 3; idx += 256) {
        int m = idx / 3;
        int o = idx - m * 3;
        int gr = mt * 128 + m;
        if (gr < MTOT) {
            float v = Yp[m * 3 + o] + Yp[(128 + m) * 3 + o];
            ypart[(((size_t)nt2 * MPAD + gr) * JN + j) * 3 + o] = v;
        }
    }
#undef DMA
#undef STAGE
#undef STEP
}

// ============================================================================
// fc2 reduce: out[gr][j][o] = b2[j][o] + sum_{s=0..7} ypart[s][gr][j][o]
// ============================================================================
__global__ __launch_bounds__(512)
void fc2_reduce(const float* __restrict__ ypart,
                const float* __restrict__ b2,
                float* __restrict__ out)
{
    int idx = blockIdx.x * 512 + threadIdx.x;      // = (gr*JN + j)*3 + o
    if (idx >= MTOT * JN * 3) return;
    int rest = idx / 3;
    int o = idx - rest * 3;
    int j = rest % JN;
    const size_t sl = (size_t)MPAD * JN * 3;
    float v = b2[j * 3 + o];
    #pragma unroll
    for (int s = 0; s < 8; ++s) v += ypart[s * sl + idx];
    out[idx] = v;
}

// ============================================================================
// Fallback v3: fused, A resident, B ring (needs only w1s ws)
// ============================================================================
#define BM3 96
#define A3_OFF 0
#define B3_OFF 98304
#define Y3_OFF 98304
#define SMEM_V3 163840

__global__ __launch_bounds__(NTHR, 2)
void pjh_fused_v3(const float* __restrict__ x,
                  const float* __restrict__ gamma,
                  const float* __restrict__ beta,
                  const ushort_t* __restrict__ w1s,
                  const float* __restrict__ b1,
                  const float* __restrict__ w2,
                  const float* __restrict__ b2,
                  float* __restrict__ out)
{
    extern __shared__ char smem[];
    const int tid  = threadIdx.x;
    const int lane = tid & 63;
    const int wv   = tid >> 6;
    const int wm   = wv >> 2;
    const int wn   = wv & 3;
    const int mt   = blockIdx.x;
    const int j    = blockIdx.y;

    const ushort_t* w1j = w1s + (size_t)j * 16 * 1024 * 32;

    #pragma unroll
    for (int tt = 0; tt < 2; ++tt) {
        const ushort_t* tb = w1j + (size_t)tt * 1024 * 32;
        #pragma unroll
        for (int qq = 0; qq < 2; ++qq) {
            const ushort_t* src = tb + (size_t)(wv * 2 + qq) * 512 + lane * 8;
            void* dst = smem + B3_OFF + tt * 16384 + (wv * 2 + qq) * 1024;
            __builtin_amdgcn_global_load_lds(
                (const __attribute__((address_space(1))) unsigned int*)src,
                (__attribute__((address_space(3))) unsigned int*)dst, 16, 0, 0);
        }
    }

    {
        const float4* gp  = (const float4*)(gamma + lane * 8);
        const float4* bpp = (const float4*)(beta + lane * 8);
        float4 g0 = gp[0], g1 = gp[1];
        float4 e0 = bpp[0], e1 = bpp[1];
        #pragma unroll
        for (int rb = 0; rb < 12; rb += 4) {
            float4 xs[4][2];
            #pragma unroll
            for (int rr = 0; rr < 4; ++rr) {
                int gr = mt * BM3 + wv * 12 + rb + rr;
                const float4* xp = (const float4*)(x + ((size_t)gr * JN + j) * DIM + lane * 8);
                xs[rr][0] = xp[0]; xs[rr][1] = xp[1];
            }
            #pragma unroll
            for (int rr = 0; rr < 4; ++rr) {
                int m = wv * 12 + rb + rr;
                float4 va = xs[rr][0], vb = xs[rr][1];
                float s  = ((va.x + va.y) + (va.z + va.w)) + ((vb.x + vb.y) + (vb.z + vb.w));
                float s2 = fmaf(va.x, va.x, fmaf(va.y, va.y, fmaf(va.z, va.z, fmaf(va.w, va.w,
                           fmaf(vb.x, vb.x, fmaf(vb.y, vb.y, fmaf(vb.z, vb.z, vb.w * vb.w)))))));
                #pragma unroll
                for (int d = 1; d < 64; d <<= 1) {
                    s  += __shfl_xor(s,  d);
                    s2 += __shfl_xor(s2, d);
                }
                float mu  = s * (1.0f / 512.0f);
                float var = s2 * (1.0f / 512.0f) - mu * mu;
                float rs  = rsqrtf(var + 1e-5f);
                float v0 = fmaf((va.x - mu) * rs, g0.x, e0.x);
                float v1 = fmaf((va.y - mu) * rs, g0.y, e0.y);
                float v2 = fmaf((va.z - mu) * rs, g0.z, e0.z);
                float v3 = fmaf((va.w - mu) * rs, g0.w, e0.w);
                float v4 = fmaf((vb.x - mu) * rs, g1.x, e1.x);
                float v5 = fmaf((vb.y - mu) * rs, g1.y, e1.y);
                float v6 = fmaf((vb.z - mu) * rs, g1.z, e1.z);
                float v7 = fmaf((vb.w - mu) * rs, g1.w, e1.w);
                uint4 qq;
                qq.x = f2bf(v0) | (f2bf(v1) << 16);
                qq.y = f2bf(v2) | (f2bf(v3) << 16);
                qq.z = f2bf(v4) | (f2bf(v5) << 16);
                qq.w = f2bf(v6) | (f2bf(v7) << 16);
                *(uint4*)(smem + A3_OFF + m * 1024 + ((lane ^ (m & 7)) * 16)) = qq;
            }
        }
    }

    __syncthreads();

    float yr[3][4][3];
    #pragma unroll
    for (int a = 0; a < 3; ++a)
        #pragma unroll
        for (int rr = 0; rr < 4; ++rr)
            #pragma unroll
            for (int o = 0; o < 3; ++o) yr[a][rr][o] = 0.f;

    const f32x4 zero4 = {0.f, 0.f, 0.f, 0.f};
    f32x4 acc[3][4];
    #pragma unroll
    for (int mf = 0; mf < 3; ++mf)
        #pragma unroll
        for (int nf = 0; nf < 4; ++nf) acc[mf][nf] = zero4;

    #pragma unroll 1
    for (int t = 0; t < 64; ++t) {
        if (t + 2 < 64) {
            int kc = (t + 2) & 15, nt = (t + 2) >> 4;
            const ushort_t* tb = w1j + ((size_t)kc * 1024 + nt * 256) * 32;
            int bb = ((t + 2) & 3) * 16384;
            #pragma unroll
            for (int qq = 0; qq < 2; ++qq) {
                const ushort_t* src = tb + (size_t)(wv * 2 + qq) * 512 + lane * 8;
                void* dst = smem + B3_OFF + bb + (wv * 2 + qq) * 1024;
                __builtin_amdgcn_global_load_lds(
                    (const __attribute__((address_space(1))) unsigned int*)src,
                    (__attribute__((address_space(3))) unsigned int*)dst, 16, 0, 0);
            }
        }

        int kc = t & 15;
        int bb = (t & 3) * 16384;
        int g  = lane >> 4;
        s16x8 aF[3], bF[4];
        #pragma unroll
        for (int mf = 0; mf < 3; ++mf) {
            int m  = wm * 48 + mf * 16 + (lane & 15);
            int ul = kc * 4 + g;
            aF[mf] = *(const s16x8*)(smem + A3_OFF + m * 1024 + ((ul ^ (m & 7)) * 16));
        }
        #pragma unroll
        for (int nf = 0; nf < 4; ++nf) {
            int nl = wn * 64 + nf * 16 + (lane & 15);
            int p  = g ^ ((nl >> 1) & 3);
            bF[nf] = *(const s16x8*)(smem + B3_OFF + bb + (nl * 4 + p) * 16);
        }

        __builtin_amdgcn_s_setprio(1);
        #pragma unroll
        for (int mf = 0; mf < 3; ++mf)
            #pragma unroll
            for (int nf = 0; nf < 4; ++nf)
                acc[mf][nf] = __builtin_amdgcn_mfma_f32_16x16x32_bf16(aF[mf], bF[nf], acc[mf][nf], 0, 0, 0);
        __builtin_amdgcn_s_setprio(0);

        if ((t & 15) == 15) {
            int nt = t >> 4;
            #pragma unroll
            for (int nf = 0; nf < 4; ++nf) {
                int n = nt * 256 + wn * 64 + nf * 16 + (lane & 15);
                float b1v = b1[j * HID + n];
                const float* w2p = w2 + ((size_t)j * HID + n) * 3;
                float w20 = w2p[0], w21 = w2p[1], w22 = w2p[2];
                #pragma unroll
                for (int mf = 0; mf < 3; ++mf) {
                    #pragma unroll
                    for (int rr = 0; rr < 4; ++rr) {
                        float gv = gelu_erf(acc[mf][nf][rr] + b1v);
                        yr[mf][rr][0] = fmaf(gv, w20, yr[mf][rr][0]);
                        yr[mf][rr][1] = fmaf(gv, w21, yr[mf][rr][1]);
                        yr[mf][rr][2] = fmaf(gv, w22, yr[mf][rr][2]);
                    }
                }
            }
            #pragma unroll
            for (int mf = 0; mf < 3; ++mf)
                #pragma unroll
                for (int nf = 0; nf < 4; ++nf)
                    acc[mf][nf] = zero4;
        }

        if (t < 62) {
            asm volatile("s_waitcnt vmcnt(2)" ::: "memory");
        } else {
            asm volatile("s_waitcnt vmcnt(0)" ::: "memory");
        }
        __builtin_amdgcn_s_barrier();
    }

    #pragma unroll
    for (int mf = 0; mf < 3; ++mf)
        #pragma unroll
        for (int rr = 0; rr < 4; ++rr)
            #pragma unroll
            for (int o = 0; o < 3; ++o) {
                float v = yr[mf][rr][o];
                v += __shfl_xor(v, 1);
                v += __shfl_xor(v, 2);
                v += __shfl_xor(v, 4);
                v += __shfl_xor(v, 8);
                yr[mf][rr][o] = v;
            }

    __syncthreads();

    float* Yp = (float*)(smem + Y3_OFF);
    if ((lane & 15) == 0) {
        int mrow = lane >> 4;
        #pragma unroll
        for (int mf = 0; mf < 3; ++mf)
            #pragma unroll
            for (int rr = 0; rr < 4; ++rr) {
                int m = wm * 48 + mf * 16 + mrow * 4 + rr;
                #pragma unroll
                for (int o = 0; o < 3; ++o)
                    Yp[(wn * BM3 + m) * 3 + o] = yr[mf][rr][o];
            }
    }
    __syncthreads();

    if (tid < BM3 * 3) {
        int m = tid / 3;
        int o = tid - m * 3;
        int gr = mt * BM3 + m;
        float v = Yp[m * 3 + o] + Yp[(BM3 + m) * 3 + o]
                + Yp[(2 * BM3 + m) * 3 + o] + Yp[(3 * BM3 + m) * 3 + o]
                + b2[j * 3 + o];
        out[((size_t)gr * JN + j) * 3 + o] = v;
    }
}

extern "C" void kernel_launch(void* const* d_in, const int* in_sizes, int n_in,
                              void* d_out, int out_size, void* d_ws, size_t ws_size,
                              hipStream_t stream) {
    (void)in_sizes; (void)n_in; (void)out_size;
    const float* x   = (const float*)d_in[0];
    const float* ga  = (const float*)d_in[1];
    const float* be  = (const float*)d_in[2];
    const float* w1  = (const float*)d_in[3];
    const float* b1  = (const float*)d_in[4];
    const float* w2  = (const float*)d_in[5];
    const float* b2  = (const float*)d_in[6];
    float* out = (float*)d_out;

    const size_t xa_bytes  = (size_t)JN * 16 * MPAD * 32 * sizeof(ushort_t);   // 135,921,664
    const size_t w1s_bytes = (size_t)JN * 16 * 1024 * 32 * sizeof(ushort_t);   // 17,825,792
    const size_t yp_bytes  = (size_t)8 * MPAD * JN * 3 * sizeof(float);        // 12,742,656

    if (ws_size >= xa_bytes + w1s_bytes + yp_bytes) {
        ushort_t* xa  = (ushort_t*)d_ws;
        ushort_t* w1s = (ushort_t*)((char*)d_ws + xa_bytes);
        float* ypart  = (float*)((char*)d_ws + xa_bytes + w1s_bytes);
        prep_xn<<<dim3(MTOT / 8, JN), NTHR, 0, stream>>>(x, ga, be, xa);
        prep_w1<<<JN * 16 * 4, 256, 0, stream>>>(w1, w1s);
        hipFuncSetAttribute((const void*)pjh_gemm_v13,
                            hipFuncAttributeMaxDynamicSharedMemorySize, SMEM_V13);
        pjh_gemm_v13<<<NWG13, 256, SMEM_V13, stream>>>(xa, w1s, b1, w2, ypart);
        fc2_reduce<<<(MTOT * JN * 3 + 511) / 512, 512, 0, stream>>>(ypart, b2, out);
    } else {
        ushort_t* w1s = (ushort_t*)d_ws;
        prep_w1<<<JN * 16 * 4, 256, 0, stream>>>(w1, w1s);
        hipFuncSetAttribute((const void*)pjh_fused_v3,
                            hipFuncAttributeMaxDynamicSharedMemorySize, SMEM_V3);
        dim3 grid(MTOT / BM3, JN);
        pjh_fused_v3<<<grid, NTHR, SMEM_V3, stream>>>(x, ga, be, w1s, b1, w2, b2, out);
    }
}